// Round 1
// baseline (730.054 us; speedup 1.0000x reference)
//
#include <hip/hip_runtime.h>

#define F_IN 48
#define F_HID 64

// ---- edge dtype detection: int64 edge_index has all-zero high words ----
__global__ void detect_i64(const int* __restrict__ e, int* __restrict__ flag) {
    __shared__ int any;
    if (threadIdx.x == 0) any = 0;
    __syncthreads();
    for (int t = threadIdx.x; t < 1024; t += blockDim.x)
        if (e[2 * t + 1] != 0) atomicOr(&any, 1);
    __syncthreads();
    if (threadIdx.x == 0) flag[0] = (any == 0) ? 1 : 0;
}

__device__ __forceinline__ int load_src(const int* e, int i, int E, int is64) {
    return e[is64 ? (long)2 * i : (long)i];
}
__device__ __forceinline__ int load_dst(const int* e, int i, int E, int is64) {
    return e[is64 ? (long)2 * (E + i) : (long)(E + i)];
}

// ---- degree count over dst (self-loop added later as +1) ----
__global__ void deg_count(const int* __restrict__ eidx, const int* __restrict__ flag,
                          float* __restrict__ deg, int E) {
    int i = blockIdx.x * blockDim.x + threadIdx.x;
    if (i >= E) return;
    int is64 = flag[0];
    int d = load_dst(eidx, i, E, is64);
    atomicAdd(&deg[d], 1.0f);
}

__global__ void dinv_k(float* __restrict__ deg, int N) {
    int i = blockIdx.x * blockDim.x + threadIdx.x;
    if (i < N) deg[i] = rsqrtf(deg[i] + 1.0f);  // deg>0 always (self-loop)
}

// ---- g1[n,f] = dinv[n] * sum_k x[n,k] * W1[k,f] ----
__global__ __launch_bounds__(256) void gemm1(const float* __restrict__ x,
                                             const float* __restrict__ W1,
                                             const float* __restrict__ dinv,
                                             float* __restrict__ g1, int N) {
    __shared__ float w[F_IN][F_HID];  // 12 KB
    __shared__ float xs[4][F_IN];
    for (int t = threadIdx.x; t < F_IN * F_HID; t += 256)
        w[t / F_HID][t % F_HID] = W1[t];
    int base = blockIdx.x * 4;
    for (int t = threadIdx.x; t < 4 * F_IN; t += 256) {
        int r = t / F_IN, k = t % F_IN;
        int n = base + r;
        xs[r][k] = (n < N) ? x[(long)n * F_IN + k] : 0.0f;
    }
    __syncthreads();
    int local = threadIdx.x >> 6, f = threadIdx.x & 63;
    int n = base + local;
    if (n >= N) return;
    float s = 0.0f;
#pragma unroll
    for (int k = 0; k < F_IN; ++k) s += xs[local][k] * w[k][f];
    g1[(long)n * F_HID + f] = s * dinv[n];
}

// ---- scatter-add layer 1: one edge per 64-lane group ----
__global__ __launch_bounds__(256) void scatter1(const int* __restrict__ eidx,
                                                const int* __restrict__ flag,
                                                const float* __restrict__ g1,
                                                float* __restrict__ agg, int E) {
    long gid = (long)blockIdx.x * blockDim.x + threadIdx.x;
    int e = (int)(gid >> 6);
    if (e >= E) return;
    int f = (int)(gid & 63);
    int is64 = flag[0];
    int s = load_src(eidx, e, E, is64);
    int d = load_dst(eidx, e, E, is64);
    atomicAdd(&agg[(long)d * F_HID + f], g1[(long)s * F_HID + f]);
}

// ---- layer1 epilogue (scale + self-loop + bias + relu) fused with h2 @ W2 ----
__global__ __launch_bounds__(256) void layer2(const float* __restrict__ agg,
                                              const float* __restrict__ g1,
                                              const float* __restrict__ dinv,
                                              const float* __restrict__ b1,
                                              const float* __restrict__ W2,
                                              float* __restrict__ g2, int N) {
    int node = blockIdx.x * 4 + (threadIdx.x >> 6);
    int f = threadIdx.x & 63;
    if (node >= N) return;
    float di = dinv[node];
    float h = di * (agg[(long)node * F_HID + f] + g1[(long)node * F_HID + f]) + b1[f];
    h = fmaxf(h, 0.0f);
    float t0 = h * W2[f * 2 + 0];
    float t1 = h * W2[f * 2 + 1];
#pragma unroll
    for (int off = 32; off > 0; off >>= 1) {
        t0 += __shfl_down(t0, off, 64);
        t1 += __shfl_down(t1, off, 64);
    }
    if (f == 0) {
        g2[node * 2 + 0] = di * t0;
        g2[node * 2 + 1] = di * t1;
    }
}

// ---- scatter-add layer 2: one edge per thread, 2 floats ----
__global__ void scatter2(const int* __restrict__ eidx, const int* __restrict__ flag,
                         const float* __restrict__ g2, float* __restrict__ acc2, int E) {
    int e = blockIdx.x * blockDim.x + threadIdx.x;
    if (e >= E) return;
    int is64 = flag[0];
    int s = load_src(eidx, e, E, is64);
    int d = load_dst(eidx, e, E, is64);
    atomicAdd(&acc2[d * 2 + 0], g2[s * 2 + 0]);
    atomicAdd(&acc2[d * 2 + 1], g2[s * 2 + 1]);
}

__global__ void finalk(const float* __restrict__ acc2, const float* __restrict__ g2,
                       const float* __restrict__ dinv, const float* __restrict__ b2,
                       float* __restrict__ out, int N) {
    int gid = blockIdx.x * blockDim.x + threadIdx.x;
    if (gid >= 2 * N) return;
    int n = gid >> 1, c = gid & 1;
    out[gid] = dinv[n] * (acc2[gid] + g2[gid]) + b2[c];
}

extern "C" void kernel_launch(void* const* d_in, const int* in_sizes, int n_in,
                              void* d_out, int out_size, void* d_ws, size_t ws_size,
                              hipStream_t stream) {
    const float* x  = (const float*)d_in[0];
    const int* eidx = (const int*)d_in[1];
    const float* W1 = (const float*)d_in[2];
    const float* b1 = (const float*)d_in[3];
    const float* W2 = (const float*)d_in[4];
    const float* b2 = (const float*)d_in[5];
    float* out = (float*)d_out;

    int N = in_sizes[0] / F_IN;   // 100000
    int E = in_sizes[1] / 2;      // 1600000

    float* ws = (float*)d_ws;
    int* flag   = (int*)ws;                    // 1 int (padded to 64 floats)
    float* deg  = ws + 64;                     // N floats; becomes dinv in place
    float* g1   = deg + N;                     // N*64
    float* agg  = g1 + (long)N * F_HID;        // N*64
    float* g2   = agg + (long)N * F_HID;       // N*2
    float* acc2 = g2 + (long)N * 2;            // N*2
    // total ~53.3 MB

    hipMemsetAsync(deg, 0, (size_t)N * sizeof(float), stream);
    hipMemsetAsync(agg, 0, (size_t)N * F_HID * sizeof(float), stream);
    hipMemsetAsync(acc2, 0, (size_t)N * 2 * sizeof(float), stream);

    detect_i64<<<1, 256, 0, stream>>>(eidx, flag);
    deg_count<<<(E + 255) / 256, 256, 0, stream>>>(eidx, flag, deg, E);
    dinv_k<<<(N + 255) / 256, 256, 0, stream>>>(deg, N);
    gemm1<<<(N + 3) / 4, 256, 0, stream>>>(x, W1, deg, g1, N);
    long t1n = (long)E * 64;
    scatter1<<<(int)((t1n + 255) / 256), 256, 0, stream>>>(eidx, flag, g1, agg, E);
    layer2<<<(N + 3) / 4, 256, 0, stream>>>(agg, g1, deg, b1, W2, g2, N);
    scatter2<<<(E + 255) / 256, 256, 0, stream>>>(eidx, flag, g2, acc2, E);
    finalk<<<(2 * N + 255) / 256, 256, 0, stream>>>(acc2, g2, deg, b2, out, N);
}

// Round 2
// 429.950 us; speedup vs baseline: 1.6980x; 1.6980x over previous
//
#include <hip/hip_runtime.h>

#define F_IN 48
#define F_HID 64

// ---- edge dtype detection: int64 edge_index has all-zero high words ----
__global__ void detect_i64(const int* __restrict__ e, int* __restrict__ flag) {
    __shared__ int any;
    if (threadIdx.x == 0) any = 0;
    __syncthreads();
    for (int t = threadIdx.x; t < 1024; t += blockDim.x)
        if (e[2 * t + 1] != 0) atomicOr(&any, 1);
    __syncthreads();
    if (threadIdx.x == 0) flag[0] = (any == 0) ? 1 : 0;
}

__device__ __forceinline__ int load_src(const int* e, int i, int E, int is64) {
    return e[is64 ? (long)2 * i : (long)i];
}
__device__ __forceinline__ int load_dst(const int* e, int i, int E, int is64) {
    return e[is64 ? (long)2 * (E + i) : (long)(E + i)];
}

// ---- int histogram over dst ----
__global__ void hist_k(const int* __restrict__ eidx, const int* __restrict__ flag,
                       int* __restrict__ deg, int E) {
    int i = blockIdx.x * blockDim.x + threadIdx.x;
    if (i >= E) return;
    int is64 = flag[0];
    atomicAdd(&deg[load_dst(eidx, i, E, is64)], 1);
}

// ---- scan step 1: per-block partial sums of deg ----
__global__ __launch_bounds__(256) void scan_reduce(const int* __restrict__ deg,
                                                   int* __restrict__ partial, int N) {
    __shared__ int s[256];
    int i = blockIdx.x * 256 + threadIdx.x;
    s[threadIdx.x] = (i < N) ? deg[i] : 0;
    __syncthreads();
    for (int off = 128; off > 0; off >>= 1) {
        if (threadIdx.x < off) s[threadIdx.x] += s[threadIdx.x + off];
        __syncthreads();
    }
    if (threadIdx.x == 0) partial[blockIdx.x] = s[0];
}

// ---- scan step 2: single-block exclusive scan of partials (nblk <= 512) ----
__global__ __launch_bounds__(512) void scan_partials(const int* __restrict__ partial,
                                                     int* __restrict__ partOff, int nblk) {
    __shared__ int s[512];
    int t = threadIdx.x;
    int orig = (t < nblk) ? partial[t] : 0;
    s[t] = orig;
    __syncthreads();
    for (int off = 1; off < 512; off <<= 1) {
        int v = (t >= off) ? s[t - off] : 0;
        __syncthreads();
        s[t] += v;
        __syncthreads();
    }
    if (t < nblk) partOff[t] = s[t] - orig;  // exclusive
}

// ---- scan step 3: block-local exclusive scan + offset; also cursor & dinv ----
__global__ __launch_bounds__(256) void scan_final(const int* __restrict__ deg,
                                                  const int* __restrict__ partOff,
                                                  int* __restrict__ rowStart,
                                                  int* __restrict__ cursor,
                                                  float* __restrict__ dinv, int N) {
    __shared__ int s[256];
    int i = blockIdx.x * 256 + threadIdx.x;
    int t = threadIdx.x;
    int orig = (i < N) ? deg[i] : 0;
    s[t] = orig;
    __syncthreads();
    for (int off = 1; off < 256; off <<= 1) {
        int v = (t >= off) ? s[t - off] : 0;
        __syncthreads();
        s[t] += v;
        __syncthreads();
    }
    if (i < N) {
        int rs = partOff[blockIdx.x] + s[t] - orig;
        rowStart[i] = rs;
        cursor[i] = rs;
        dinv[i] = rsqrtf((float)orig + 1.0f);
    }
}

// ---- counting-sort placement: srcSorted grouped by dst ----
__global__ void place_k(const int* __restrict__ eidx, const int* __restrict__ flag,
                        int* __restrict__ cursor, int* __restrict__ srcSorted, int E) {
    int i = blockIdx.x * blockDim.x + threadIdx.x;
    if (i >= E) return;
    int is64 = flag[0];
    int s = load_src(eidx, i, E, is64);
    int d = load_dst(eidx, i, E, is64);
    int pos = atomicAdd(&cursor[d], 1);
    srcSorted[pos] = s;
}

// ---- fused: 48-dim CSR aggregation + GEMM1 + bias + relu + W2 matvec -> g2 ----
__global__ __launch_bounds__(256) void fused1(const float* __restrict__ x,
                                              const float* __restrict__ W1,
                                              const float* __restrict__ b1,
                                              const float* __restrict__ W2,
                                              const float* __restrict__ dinv,
                                              const int* __restrict__ rowStart,
                                              const int* __restrict__ deg,
                                              const int* __restrict__ srcSorted,
                                              float* __restrict__ g2, int N) {
    int wave = threadIdx.x >> 6, lane = threadIdx.x & 63;
    int node = blockIdx.x * 4 + wave;
    if (node >= N) return;

    // W1 column for this lane's output feature (L1-resident, shared by all waves)
    float w1c[F_IN];
#pragma unroll
    for (int k = 0; k < F_IN; ++k) w1c[k] = W1[k * F_HID + lane];

    int rs = rowStart[node];
    int re = rs + deg[node];
    float acc = 0.0f;
    int j = rs;
    for (; j + 1 < re; j += 2) {  // unroll x2 for load ILP
        int s0 = srcSorted[j], s1 = srcSorted[j + 1];
        float d0 = dinv[s0], d1 = dinv[s1];
        float x0 = (lane < F_IN) ? x[(long)s0 * F_IN + lane] : 0.0f;
        float x1 = (lane < F_IN) ? x[(long)s1 * F_IN + lane] : 0.0f;
        acc += d0 * x0;
        acc += d1 * x1;
    }
    if (j < re) {
        int s0 = srcSorted[j];
        float d0 = dinv[s0];
        float x0 = (lane < F_IN) ? x[(long)s0 * F_IN + lane] : 0.0f;
        acc += d0 * x0;
    }
    float di = dinv[node];
    float selfv = (lane < F_IN) ? x[(long)node * F_IN + lane] : 0.0f;
    float v = di * (acc + di * selfv);  // lane t<48 holds v[t]

    // h[f] = relu(sum_k v[k]*W1[k][f] + b1[f]) via lane-broadcast
    float h = b1[lane];
#pragma unroll
    for (int k = 0; k < F_IN; ++k) h += __shfl(v, k, 64) * w1c[k];
    h = fmaxf(h, 0.0f);

    // g2[node] = dinv * (h @ W2)   (2 outputs, shuffle reduce over 64 lanes)
    float t0 = h * W2[lane * 2 + 0];
    float t1 = h * W2[lane * 2 + 1];
#pragma unroll
    for (int off = 32; off > 0; off >>= 1) {
        t0 += __shfl_down(t0, off, 64);
        t1 += __shfl_down(t1, off, 64);
    }
    if (lane == 0) ((float2*)g2)[node] = make_float2(di * t0, di * t1);
}

// ---- layer-2 CSR aggregation (g2 is L2-resident) + final epilogue ----
__global__ void agg2(const int* __restrict__ rowStart, const int* __restrict__ deg,
                     const int* __restrict__ srcSorted, const float* __restrict__ g2,
                     const float* __restrict__ dinv, const float* __restrict__ b2,
                     float* __restrict__ out, int N) {
    int n = blockIdx.x * blockDim.x + threadIdx.x;
    if (n >= N) return;
    int rs = rowStart[n], re = rs + deg[n];
    float a0 = 0.0f, a1 = 0.0f;
    int j = rs;
    for (; j + 1 < re; j += 2) {
        int s0 = srcSorted[j], s1 = srcSorted[j + 1];
        float2 v0 = ((const float2*)g2)[s0];
        float2 v1 = ((const float2*)g2)[s1];
        a0 += v0.x + v1.x;
        a1 += v0.y + v1.y;
    }
    if (j < re) {
        float2 v0 = ((const float2*)g2)[srcSorted[j]];
        a0 += v0.x;
        a1 += v0.y;
    }
    float2 self = ((const float2*)g2)[n];
    float di = dinv[n];
    out[2 * n + 0] = di * (a0 + self.x) + b2[0];
    out[2 * n + 1] = di * (a1 + self.y) + b2[1];
}

extern "C" void kernel_launch(void* const* d_in, const int* in_sizes, int n_in,
                              void* d_out, int out_size, void* d_ws, size_t ws_size,
                              hipStream_t stream) {
    const float* x  = (const float*)d_in[0];
    const int* eidx = (const int*)d_in[1];
    const float* W1 = (const float*)d_in[2];
    const float* b1 = (const float*)d_in[3];
    const float* W2 = (const float*)d_in[4];
    const float* b2 = (const float*)d_in[5];
    float* out = (float*)d_out;

    int N = in_sizes[0] / F_IN;   // 100000
    int E = in_sizes[1] / 2;      // 1600000
    int nblk = (N + 255) / 256;   // 391 (<=512 required by scan_partials)

    char* ws = (char*)d_ws;
    int*   flag      = (int*)ws;                       ws += 256;
    int*   deg       = (int*)ws;                       ws += (size_t)N * 4;
    int*   rowStart  = (int*)ws;                       ws += (size_t)N * 4;
    int*   cursor    = (int*)ws;                       ws += (size_t)N * 4;
    int*   partial   = (int*)ws;                       ws += 512 * 4;
    int*   partOff   = (int*)ws;                       ws += 512 * 4;
    int*   srcSorted = (int*)ws;                       ws += (size_t)E * 4;
    float* dinv      = (float*)ws;                     ws += (size_t)N * 4;
    float* g2        = (float*)ws;                     ws += (size_t)N * 2 * 4;

    hipMemsetAsync(deg, 0, (size_t)N * sizeof(int), stream);

    detect_i64<<<1, 256, 0, stream>>>(eidx, flag);
    hist_k<<<(E + 255) / 256, 256, 0, stream>>>(eidx, flag, deg, E);
    scan_reduce<<<nblk, 256, 0, stream>>>(deg, partial, N);
    scan_partials<<<1, 512, 0, stream>>>(partial, partOff, nblk);
    scan_final<<<nblk, 256, 0, stream>>>(deg, partOff, rowStart, cursor, dinv, N);
    place_k<<<(E + 255) / 256, 256, 0, stream>>>(eidx, flag, cursor, srcSorted, E);
    fused1<<<(N + 3) / 4, 256, 0, stream>>>(x, W1, b1, W2, dinv, rowStart, deg,
                                            srcSorted, g2, N);
    agg2<<<(N + 255) / 256, 256, 0, stream>>>(rowStart, deg, srcSorted, g2, dinv,
                                              b2, out, N);
}

// Round 3
// 376.001 us; speedup vs baseline: 1.9416x; 1.1435x over previous
//
#include <hip/hip_runtime.h>
#include <hip/hip_fp16.h>

#define F_IN 48
#define F_HID 64

// ---- edge dtype detection: int64 edge_index has all-zero high words ----
__global__ void detect_i64(const int* __restrict__ e, int* __restrict__ flag) {
    __shared__ int any;
    if (threadIdx.x == 0) any = 0;
    __syncthreads();
    for (int t = threadIdx.x; t < 1024; t += blockDim.x)
        if (e[2 * t + 1] != 0) atomicOr(&any, 1);
    __syncthreads();
    if (threadIdx.x == 0) flag[0] = (any == 0) ? 1 : 0;
}

__device__ __forceinline__ int load_src(const int* e, int i, int E, int is64) {
    return e[is64 ? (long)2 * i : (long)i];
}
__device__ __forceinline__ int load_dst(const int* e, int i, int E, int is64) {
    return e[is64 ? (long)2 * (E + i) : (long)(E + i)];
}

// ---- int histogram over dst ----
__global__ void hist_k(const int* __restrict__ eidx, const int* __restrict__ flag,
                       int* __restrict__ deg, int E) {
    int i = blockIdx.x * blockDim.x + threadIdx.x;
    if (i >= E) return;
    int is64 = flag[0];
    atomicAdd(&deg[load_dst(eidx, i, E, is64)], 1);
}

// ---- scan step 1: per-block partial sums of deg ----
__global__ __launch_bounds__(256) void scan_reduce(const int* __restrict__ deg,
                                                   int* __restrict__ partial, int N) {
    __shared__ int s[256];
    int i = blockIdx.x * 256 + threadIdx.x;
    s[threadIdx.x] = (i < N) ? deg[i] : 0;
    __syncthreads();
    for (int off = 128; off > 0; off >>= 1) {
        if (threadIdx.x < off) s[threadIdx.x] += s[threadIdx.x + off];
        __syncthreads();
    }
    if (threadIdx.x == 0) partial[blockIdx.x] = s[0];
}

// ---- scan step 2: single-block exclusive scan of partials (nblk <= 512) ----
__global__ __launch_bounds__(512) void scan_partials(const int* __restrict__ partial,
                                                     int* __restrict__ partOff, int nblk) {
    __shared__ int s[512];
    int t = threadIdx.x;
    int orig = (t < nblk) ? partial[t] : 0;
    s[t] = orig;
    __syncthreads();
    for (int off = 1; off < 512; off <<= 1) {
        int v = (t >= off) ? s[t - off] : 0;
        __syncthreads();
        s[t] += v;
        __syncthreads();
    }
    if (t < nblk) partOff[t] = s[t] - orig;  // exclusive
}

// ---- scan step 3: block-local exclusive scan + offset; also cursor & dinv ----
__global__ __launch_bounds__(256) void scan_final(const int* __restrict__ deg,
                                                  const int* __restrict__ partOff,
                                                  int* __restrict__ rowStart,
                                                  int* __restrict__ cursor,
                                                  float* __restrict__ dinv, int N) {
    __shared__ int s[256];
    int i = blockIdx.x * 256 + threadIdx.x;
    int t = threadIdx.x;
    int orig = (i < N) ? deg[i] : 0;
    s[t] = orig;
    __syncthreads();
    for (int off = 1; off < 256; off <<= 1) {
        int v = (t >= off) ? s[t - off] : 0;
        __syncthreads();
        s[t] += v;
        __syncthreads();
    }
    if (i < N) {
        int rs = partOff[blockIdx.x] + s[t] - orig;
        rowStart[i] = rs;
        cursor[i] = rs;
        dinv[i] = rsqrtf((float)orig + 1.0f);
    }
}

// ---- counting-sort placement: srcSorted grouped by dst ----
__global__ void place_k(const int* __restrict__ eidx, const int* __restrict__ flag,
                        int* __restrict__ cursor, int* __restrict__ srcSorted, int E) {
    int i = blockIdx.x * blockDim.x + threadIdx.x;
    if (i >= E) return;
    int is64 = flag[0];
    int s = load_src(eidx, i, E, is64);
    int d = load_dst(eidx, i, E, is64);
    int pos = atomicAdd(&cursor[d], 1);
    srcSorted[pos] = s;
}

// ---- y16[n][k] = half(dinv[n] * x[n][k]), rows padded to 64 (one 128B line) ----
__global__ __launch_bounds__(256) void prep_y(const float* __restrict__ x,
                                              const float* __restrict__ dinv,
                                              __half* __restrict__ y, int N) {
    int t = blockIdx.x * 256 + threadIdx.x;
    if (t >= N * 64) return;
    int n = t >> 6, k = t & 63;
    float v = (k < F_IN) ? dinv[n] * x[(long)n * F_IN + k] : 0.0f;
    y[t] = __float2half(v);
}

// ---- fused: fp16 CSR aggregation (scalar index stream) + GEMM1 + relu + W2 ----
__global__ __launch_bounds__(256) void fused1(const __half* __restrict__ y,
                                              const float* __restrict__ W1,
                                              const float* __restrict__ b1,
                                              const float* __restrict__ W2,
                                              const float* __restrict__ dinv,
                                              const int* __restrict__ rowStart,
                                              const int* __restrict__ deg,
                                              const int* __restrict__ srcSorted,
                                              float* __restrict__ g2, int N) {
    int lane = threadIdx.x & 63;
    // wave-uniform node index -> SGPR; all downstream index loads become s_load
    int node = __builtin_amdgcn_readfirstlane(blockIdx.x * 4 + (threadIdx.x >> 6));
    if (node >= N) return;
    int rs = __builtin_amdgcn_readfirstlane(rowStart[node]);
    int dn = __builtin_amdgcn_readfirstlane(deg[node]);

    float acc = 0.0f;
    int j = 0;
    for (; j + 8 <= dn; j += 8) {  // 8 gathers in flight, scalar indices
        float t0, t1, t2, t3, t4, t5, t6, t7;
        {
            int s0 = __builtin_amdgcn_readfirstlane(srcSorted[rs + j + 0]);
            int s1 = __builtin_amdgcn_readfirstlane(srcSorted[rs + j + 1]);
            int s2 = __builtin_amdgcn_readfirstlane(srcSorted[rs + j + 2]);
            int s3 = __builtin_amdgcn_readfirstlane(srcSorted[rs + j + 3]);
            int s4 = __builtin_amdgcn_readfirstlane(srcSorted[rs + j + 4]);
            int s5 = __builtin_amdgcn_readfirstlane(srcSorted[rs + j + 5]);
            int s6 = __builtin_amdgcn_readfirstlane(srcSorted[rs + j + 6]);
            int s7 = __builtin_amdgcn_readfirstlane(srcSorted[rs + j + 7]);
            t0 = __half2float(y[((long)s0 << 6) + lane]);
            t1 = __half2float(y[((long)s1 << 6) + lane]);
            t2 = __half2float(y[((long)s2 << 6) + lane]);
            t3 = __half2float(y[((long)s3 << 6) + lane]);
            t4 = __half2float(y[((long)s4 << 6) + lane]);
            t5 = __half2float(y[((long)s5 << 6) + lane]);
            t6 = __half2float(y[((long)s6 << 6) + lane]);
            t7 = __half2float(y[((long)s7 << 6) + lane]);
        }
        acc += ((t0 + t1) + (t2 + t3)) + ((t4 + t5) + (t6 + t7));
    }
    for (; j < dn; ++j) {
        int s0 = __builtin_amdgcn_readfirstlane(srcSorted[rs + j]);
        acc += __half2float(y[((long)s0 << 6) + lane]);
    }

    float di = dinv[node];
    float yself = __half2float(y[((long)node << 6) + lane]);
    float v = di * (acc + yself);  // lane t<48 holds v[t]; pad lanes are 0

    // h[f] = relu(sum_k v[k]*W1[k][f] + b1[f]) via lane-broadcast
    float h = b1[lane];
#pragma unroll
    for (int k = 0; k < F_IN; ++k)
        h = fmaf(__shfl(v, k, 64), W1[k * F_HID + lane], h);
    h = fmaxf(h, 0.0f);

    // g2[node] = dinv * (h @ W2)
    float t0 = h * W2[lane * 2 + 0];
    float t1 = h * W2[lane * 2 + 1];
#pragma unroll
    for (int off = 32; off > 0; off >>= 1) {
        t0 += __shfl_down(t0, off, 64);
        t1 += __shfl_down(t1, off, 64);
    }
    if (lane == 0) ((float2*)g2)[node] = make_float2(di * t0, di * t1);
}

// ---- layer-2 CSR aggregation (g2 is L2-resident) + final epilogue ----
__global__ void agg2(const int* __restrict__ rowStart, const int* __restrict__ deg,
                     const int* __restrict__ srcSorted, const float* __restrict__ g2,
                     const float* __restrict__ dinv, const float* __restrict__ b2,
                     float* __restrict__ out, int N) {
    int n = blockIdx.x * blockDim.x + threadIdx.x;
    if (n >= N) return;
    const float2* g2v = (const float2*)g2;
    int rs = rowStart[n], dn = deg[n];
    float a0 = 0.0f, a1 = 0.0f;
    int j = 0;
    for (; j + 4 <= dn; j += 4) {
        int s0 = srcSorted[rs + j + 0];
        int s1 = srcSorted[rs + j + 1];
        int s2 = srcSorted[rs + j + 2];
        int s3 = srcSorted[rs + j + 3];
        float2 v0 = g2v[s0], v1 = g2v[s1], v2 = g2v[s2], v3 = g2v[s3];
        a0 += (v0.x + v1.x) + (v2.x + v3.x);
        a1 += (v0.y + v1.y) + (v2.y + v3.y);
    }
    for (; j < dn; ++j) {
        float2 v0 = g2v[srcSorted[rs + j]];
        a0 += v0.x;
        a1 += v0.y;
    }
    float2 self = g2v[n];
    float di = dinv[n];
    out[2 * n + 0] = di * (a0 + self.x) + b2[0];
    out[2 * n + 1] = di * (a1 + self.y) + b2[1];
}

extern "C" void kernel_launch(void* const* d_in, const int* in_sizes, int n_in,
                              void* d_out, int out_size, void* d_ws, size_t ws_size,
                              hipStream_t stream) {
    const float* x  = (const float*)d_in[0];
    const int* eidx = (const int*)d_in[1];
    const float* W1 = (const float*)d_in[2];
    const float* b1 = (const float*)d_in[3];
    const float* W2 = (const float*)d_in[4];
    const float* b2 = (const float*)d_in[5];
    float* out = (float*)d_out;

    int N = in_sizes[0] / F_IN;   // 100000
    int E = in_sizes[1] / 2;      // 1600000
    int nblk = (N + 255) / 256;   // 391 (<=512 required by scan_partials)

    char* ws = (char*)d_ws;
    int*    flag      = (int*)ws;      ws += 256;
    int*    deg       = (int*)ws;      ws += (size_t)N * 4;
    int*    rowStart  = (int*)ws;      ws += (size_t)N * 4;
    int*    cursor    = (int*)ws;      ws += (size_t)N * 4;
    int*    partial   = (int*)ws;      ws += 512 * 4;
    int*    partOff   = (int*)ws;      ws += 512 * 4;
    int*    srcSorted = (int*)ws;      ws += (size_t)E * 4;
    float*  dinv      = (float*)ws;    ws += (size_t)N * 4;
    float*  g2        = (float*)ws;    ws += (size_t)N * 2 * 4;
    ws = (char*)(((size_t)ws + 255) & ~(size_t)255);
    __half* y16       = (__half*)ws;   ws += (size_t)N * 64 * 2;  // padded rows

    hipMemsetAsync(deg, 0, (size_t)N * sizeof(int), stream);

    detect_i64<<<1, 256, 0, stream>>>(eidx, flag);
    hist_k<<<(E + 255) / 256, 256, 0, stream>>>(eidx, flag, deg, E);
    scan_reduce<<<nblk, 256, 0, stream>>>(deg, partial, N);
    scan_partials<<<1, 512, 0, stream>>>(partial, partOff, nblk);
    scan_final<<<nblk, 256, 0, stream>>>(deg, partOff, rowStart, cursor, dinv, N);
    prep_y<<<(N * 64 + 255) / 256, 256, 0, stream>>>(x, dinv, y16, N);
    place_k<<<(E + 255) / 256, 256, 0, stream>>>(eidx, flag, cursor, srcSorted, E);
    fused1<<<(N + 3) / 4, 256, 0, stream>>>(y16, W1, b1, W2, dinv, rowStart, deg,
                                            srcSorted, g2, N);
    agg2<<<(N + 255) / 256, 256, 0, stream>>>(rowStart, deg, srcSorted, g2, dinv,
                                              b2, out, N);
}

// Round 4
// 226.969 us; speedup vs baseline: 3.2165x; 1.6566x over previous
//
#include <hip/hip_runtime.h>
#include <hip/hip_fp16.h>

#define F_IN 48
#define F_HID 64
#define GSH 7            // nodes per bucket = 128
#define GSZ 128
#define MAXB 1024        // supports N <= 131072 (pack: src in 17 bits, g in 7)
#define CHUNK 4096       // edges per passA block (16 per thread)

// ---- edge dtype detection: int64 edge_index has all-zero high words ----
__global__ void detect_i64(const int* __restrict__ e, int* __restrict__ flag) {
    __shared__ int any;
    if (threadIdx.x == 0) any = 0;
    __syncthreads();
    for (int t = threadIdx.x; t < 1024; t += blockDim.x)
        if (e[2 * t + 1] != 0) atomicOr(&any, 1);
    __syncthreads();
    if (threadIdx.x == 0) flag[0] = (any == 0) ? 1 : 0;
}

__device__ __forceinline__ int load_src(const int* e, int i, int E, int is64) {
    return e[is64 ? (long)2 * i : (long)i];
}
__device__ __forceinline__ int load_dst(const int* e, int i, int E, int is64) {
    return e[is64 ? (long)2 * (E + i) : (long)(E + i)];
}

// ---- coarse bucket histogram (LDS pre-aggregated) ----
__global__ __launch_bounds__(256) void bhist(const int* __restrict__ eidx,
                                             const int* __restrict__ flag,
                                             int* __restrict__ bcnt, int E, int B) {
    __shared__ int lcnt[MAXB];
    for (int t = threadIdx.x; t < B; t += 256) lcnt[t] = 0;
    __syncthreads();
    int is64 = flag[0];
    int stride = gridDim.x * 256;
    for (int i = blockIdx.x * 256 + threadIdx.x; i < E; i += stride)
        atomicAdd(&lcnt[load_dst(eidx, i, E, is64) >> GSH], 1);
    __syncthreads();
    for (int t = threadIdx.x; t < B; t += 256) {
        int c = lcnt[t];
        if (c) atomicAdd(&bcnt[t], c);
    }
}

// ---- single-block exclusive scan of bucket counts -> bstart, bcur ----
__global__ __launch_bounds__(1024) void bscan(const int* __restrict__ bcnt,
                                              int* __restrict__ bstart,
                                              int* __restrict__ bcur, int B) {
    __shared__ int s[1024];
    int t = threadIdx.x;
    int v = (t < B) ? bcnt[t] : 0;
    s[t] = v;
    __syncthreads();
    for (int off = 1; off < 1024; off <<= 1) {
        int u = (t >= off) ? s[t - off] : 0;
        __syncthreads();
        s[t] += u;
        __syncthreads();
    }
    int ex = s[t] - v;
    if (t < B) { bstart[t] = ex; bcur[t] = ex; }
    if (t == B - 1) bstart[B] = ex + v;
}

// ---- pass A: bucket edges; per-block chunk reservation keeps writes L2-hot ----
__global__ __launch_bounds__(256) void passA(const int* __restrict__ eidx,
                                             const int* __restrict__ flag,
                                             int* __restrict__ bcur,
                                             int* __restrict__ ebuf, int E) {
    __shared__ int lcnt[MAXB], lbase[MAXB];
    int base = blockIdx.x * CHUNK;
    int is64 = flag[0];
    for (int t = threadIdx.x; t < MAXB; t += 256) lcnt[t] = 0;
    __syncthreads();
    int pk[16], bk[16];
    int cnt = 0;
#pragma unroll
    for (int r = 0; r < 16; ++r) {
        int i = base + r * 256 + threadIdx.x;
        if (i < E) {
            int s = load_src(eidx, i, E, is64);
            int d = load_dst(eidx, i, E, is64);
            pk[r] = s | ((d & (GSZ - 1)) << 17);
            bk[r] = d >> GSH;
            atomicAdd(&lcnt[bk[r]], 1);
            cnt = r + 1;
        }
    }
    __syncthreads();
    for (int t = threadIdx.x; t < MAXB; t += 256) {
        int c = lcnt[t];
        lbase[t] = c ? atomicAdd(&bcur[t], c) : 0;
    }
    __syncthreads();
    for (int t = threadIdx.x; t < MAXB; t += 256) lcnt[t] = 0;
    __syncthreads();
    for (int r = 0; r < cnt; ++r) {
        int b = bk[r];
        int off = atomicAdd(&lcnt[b], 1);
        ebuf[lbase[b] + off] = pk[r];
    }
}

// ---- pass B: one WG per bucket -> deg/rowStart/dinv + contiguous srcSorted ----
__global__ __launch_bounds__(256) void passB(const int* __restrict__ ebuf,
                                             const int* __restrict__ bstart,
                                             int* __restrict__ rowStart,
                                             int* __restrict__ deg,
                                             float* __restrict__ dinv,
                                             int* __restrict__ srcSorted, int N) {
    __shared__ int cnt[GSZ], off[GSZ], cur[GSZ];
    int b = blockIdx.x;
    int s0 = bstart[b], s1 = bstart[b + 1];
    int t = threadIdx.x;
    if (t < GSZ) cnt[t] = 0;
    __syncthreads();
    for (int e = s0 + t; e < s1; e += 256)
        atomicAdd(&cnt[ebuf[e] >> 17], 1);
    __syncthreads();
    if (t < GSZ) off[t] = cnt[t];
    __syncthreads();
    for (int o = 1; o < GSZ; o <<= 1) {
        int v = (t < GSZ && t >= o) ? off[t - o] : 0;
        __syncthreads();
        if (t < GSZ) off[t] += v;
        __syncthreads();
    }
    if (t < GSZ) {
        int ex = off[t] - cnt[t];   // exclusive
        cur[t] = ex;
        int node = (b << GSH) + t;
        if (node < N) {
            rowStart[node] = s0 + ex;
            deg[node] = cnt[t];
            dinv[node] = rsqrtf((float)cnt[t] + 1.0f);
        }
    }
    __syncthreads();
    for (int e = s0 + t; e < s1; e += 256) {
        int pk = ebuf[e];
        int p = atomicAdd(&cur[pk >> 17], 1);
        srcSorted[s0 + p] = pk & 0x1FFFF;
    }
}

// ---- y16[n][k] = half(dinv[n] * x[n][k]), rows padded to 64 (one 128B line) ----
__global__ __launch_bounds__(256) void prep_y(const float* __restrict__ x,
                                              const float* __restrict__ dinv,
                                              __half* __restrict__ y, int N) {
    int t = blockIdx.x * 256 + threadIdx.x;
    if (t >= N * 64) return;
    int n = t >> 6, k = t & 63;
    float v = (k < F_IN) ? dinv[n] * x[(long)n * F_IN + k] : 0.0f;
    y[t] = __float2half(v);
}

// ---- fused: fp16 CSR aggregation (scalar index stream) + GEMM1 + relu + W2 ----
__global__ __launch_bounds__(256) void fused1(const __half* __restrict__ y,
                                              const float* __restrict__ W1,
                                              const float* __restrict__ b1,
                                              const float* __restrict__ W2,
                                              const float* __restrict__ dinv,
                                              const int* __restrict__ rowStart,
                                              const int* __restrict__ deg,
                                              const int* __restrict__ srcSorted,
                                              float* __restrict__ g2, int N) {
    int lane = threadIdx.x & 63;
    int node = __builtin_amdgcn_readfirstlane(blockIdx.x * 4 + (threadIdx.x >> 6));
    if (node >= N) return;
    int rs = __builtin_amdgcn_readfirstlane(rowStart[node]);
    int dn = __builtin_amdgcn_readfirstlane(deg[node]);

    float acc = 0.0f;
    int j = 0;
    for (; j + 8 <= dn; j += 8) {
        int s0 = __builtin_amdgcn_readfirstlane(srcSorted[rs + j + 0]);
        int s1 = __builtin_amdgcn_readfirstlane(srcSorted[rs + j + 1]);
        int s2 = __builtin_amdgcn_readfirstlane(srcSorted[rs + j + 2]);
        int s3 = __builtin_amdgcn_readfirstlane(srcSorted[rs + j + 3]);
        int s4 = __builtin_amdgcn_readfirstlane(srcSorted[rs + j + 4]);
        int s5 = __builtin_amdgcn_readfirstlane(srcSorted[rs + j + 5]);
        int s6 = __builtin_amdgcn_readfirstlane(srcSorted[rs + j + 6]);
        int s7 = __builtin_amdgcn_readfirstlane(srcSorted[rs + j + 7]);
        float t0 = __half2float(y[((long)s0 << 6) + lane]);
        float t1 = __half2float(y[((long)s1 << 6) + lane]);
        float t2 = __half2float(y[((long)s2 << 6) + lane]);
        float t3 = __half2float(y[((long)s3 << 6) + lane]);
        float t4 = __half2float(y[((long)s4 << 6) + lane]);
        float t5 = __half2float(y[((long)s5 << 6) + lane]);
        float t6 = __half2float(y[((long)s6 << 6) + lane]);
        float t7 = __half2float(y[((long)s7 << 6) + lane]);
        acc += ((t0 + t1) + (t2 + t3)) + ((t4 + t5) + (t6 + t7));
    }
    for (; j < dn; ++j) {
        int s0 = __builtin_amdgcn_readfirstlane(srcSorted[rs + j]);
        acc += __half2float(y[((long)s0 << 6) + lane]);
    }

    float di = dinv[node];
    float yself = __half2float(y[((long)node << 6) + lane]);
    float v = di * (acc + yself);

    float h = b1[lane];
#pragma unroll
    for (int k = 0; k < F_IN; ++k)
        h = fmaf(__shfl(v, k, 64), W1[k * F_HID + lane], h);
    h = fmaxf(h, 0.0f);

    float t0 = h * W2[lane * 2 + 0];
    float t1 = h * W2[lane * 2 + 1];
#pragma unroll
    for (int off = 32; off > 0; off >>= 1) {
        t0 += __shfl_down(t0, off, 64);
        t1 += __shfl_down(t1, off, 64);
    }
    if (lane == 0) ((float2*)g2)[node] = make_float2(di * t0, di * t1);
}

// ---- layer-2 CSR aggregation (g2 is L2-resident) + final epilogue ----
__global__ void agg2(const int* __restrict__ rowStart, const int* __restrict__ deg,
                     const int* __restrict__ srcSorted, const float* __restrict__ g2,
                     const float* __restrict__ dinv, const float* __restrict__ b2,
                     float* __restrict__ out, int N) {
    int n = blockIdx.x * blockDim.x + threadIdx.x;
    if (n >= N) return;
    const float2* g2v = (const float2*)g2;
    int rs = rowStart[n], dn = deg[n];
    float a0 = 0.0f, a1 = 0.0f;
    int j = 0;
    for (; j + 4 <= dn; j += 4) {
        int s0 = srcSorted[rs + j + 0];
        int s1 = srcSorted[rs + j + 1];
        int s2 = srcSorted[rs + j + 2];
        int s3 = srcSorted[rs + j + 3];
        float2 v0 = g2v[s0], v1 = g2v[s1], v2 = g2v[s2], v3 = g2v[s3];
        a0 += (v0.x + v1.x) + (v2.x + v3.x);
        a1 += (v0.y + v1.y) + (v2.y + v3.y);
    }
    for (; j < dn; ++j) {
        float2 v0 = g2v[srcSorted[rs + j]];
        a0 += v0.x;
        a1 += v0.y;
    }
    float2 self = g2v[n];
    float di = dinv[n];
    out[2 * n + 0] = di * (a0 + self.x) + b2[0];
    out[2 * n + 1] = di * (a1 + self.y) + b2[1];
}

extern "C" void kernel_launch(void* const* d_in, const int* in_sizes, int n_in,
                              void* d_out, int out_size, void* d_ws, size_t ws_size,
                              hipStream_t stream) {
    const float* x  = (const float*)d_in[0];
    const int* eidx = (const int*)d_in[1];
    const float* W1 = (const float*)d_in[2];
    const float* b1 = (const float*)d_in[3];
    const float* W2 = (const float*)d_in[4];
    const float* b2 = (const float*)d_in[5];
    float* out = (float*)d_out;

    int N = in_sizes[0] / F_IN;   // 100000
    int E = in_sizes[1] / 2;      // 1600000
    int B = (N + GSZ - 1) >> GSH; // 782 buckets (<= MAXB)

    char* ws = (char*)d_ws;
    int*    flag      = (int*)ws;      ws += 256;
    int*    bcnt      = (int*)ws;      ws += MAXB * 4;
    int*    bstart    = (int*)ws;      ws += (MAXB + 1) * 4;
    int*    bcur      = (int*)ws;      ws += MAXB * 4;
    int*    deg       = (int*)ws;      ws += (size_t)N * 4;
    int*    rowStart  = (int*)ws;      ws += (size_t)N * 4;
    float*  dinv      = (float*)ws;    ws += (size_t)N * 4;
    int*    srcSorted = (int*)ws;      ws += (size_t)E * 4;
    int*    ebuf      = (int*)ws;      ws += (size_t)E * 4;
    float*  g2        = (float*)ws;    ws += (size_t)N * 2 * 4;
    ws = (char*)(((size_t)ws + 255) & ~(size_t)255);
    __half* y16       = (__half*)ws;   ws += (size_t)N * 64 * 2;

    hipMemsetAsync(bcnt, 0, MAXB * sizeof(int), stream);

    detect_i64<<<1, 256, 0, stream>>>(eidx, flag);
    bhist<<<256, 256, 0, stream>>>(eidx, flag, bcnt, E, B);
    bscan<<<1, 1024, 0, stream>>>(bcnt, bstart, bcur, B);
    passA<<<(E + CHUNK - 1) / CHUNK, 256, 0, stream>>>(eidx, flag, bcur, ebuf, E);
    passB<<<B, 256, 0, stream>>>(ebuf, bstart, rowStart, deg, dinv, srcSorted, N);
    prep_y<<<(N * 64 + 255) / 256, 256, 0, stream>>>(x, dinv, y16, N);
    fused1<<<(N + 3) / 4, 256, 0, stream>>>(y16, W1, b1, W2, dinv, rowStart, deg,
                                            srcSorted, g2, N);
    agg2<<<(N + 255) / 256, 256, 0, stream>>>(rowStart, deg, srcSorted, g2, dinv,
                                              b2, out, N);
}